// Round 3
// baseline (99.019 us; speedup 1.0000x reference)
//
#include <hip/hip_runtime.h>

#define BATCH 8
#define ROWS  2048
#define WIDTH 4096
#define COLS  4096
#define KB    1024   // WIDTH / 4 (gating blocks along k)
#define CB    1024   // COLS  / 4 (gating blocks along c)

#define NCOLSUM 512      // colsum blocks; each owns 32 contiguous rows (512 KB)
#define SLABROWS 32

// ---------------------------------------------------------------------------
// Fused kernel, 1536 blocks:
//   [0, 512):    colsum — xs[b,k] = sum_r X[b,r,k]. Each block streams a
//                CONTIGUOUS 512 KB slab (32 full rows); per-thread static
//                accumulators for k4 = {tid, tid+256, tid+512, tid+768};
//                atomicAdd into zeroed xs at the end.
//   [512, 1536): gate — wg[b,k] = sum_c W[k,c]*G[b,k/4,c/4], one block per kb.
// ---------------------------------------------------------------------------
__global__ __launch_bounds__(256) void fused_kernel(const float4* __restrict__ Xv,
                                                    const float4* __restrict__ Wv,
                                                    const float* __restrict__ G,
                                                    float* __restrict__ xs,
                                                    float* __restrict__ wg) {
    const int tid = threadIdx.x;
    if (blockIdx.x < NCOLSUM) {
        // ---------------- colsum: contiguous slab stream --------------------
        const int s  = blockIdx.x;          // slab id
        const int b  = s >> 6;              // 64 slabs per batch (2048/32)
        const int r0 = (s & 63) * SLABROWS;
        const float4* p = Xv + (size_t)(b * ROWS + r0) * (WIDTH / 4) + tid;

        float4 a0 = {0, 0, 0, 0}, a1 = {0, 0, 0, 0}, a2 = {0, 0, 0, 0}, a3 = {0, 0, 0, 0};
#pragma unroll 2
        for (int ii = 0; ii < SLABROWS; ++ii) {
            const float4* row = p + (size_t)ii * (WIDTH / 4);
            float4 v0 = row[0];
            float4 v1 = row[256];
            float4 v2 = row[512];
            float4 v3 = row[768];
            a0.x += v0.x; a0.y += v0.y; a0.z += v0.z; a0.w += v0.w;
            a1.x += v1.x; a1.y += v1.y; a1.z += v1.z; a1.w += v1.w;
            a2.x += v2.x; a2.y += v2.y; a2.z += v2.z; a2.w += v2.w;
            a3.x += v3.x; a3.y += v3.y; a3.z += v3.z; a3.w += v3.w;
        }
        float* dst = xs + (size_t)b * WIDTH;
        atomicAdd(dst + 4 * (0 * 256 + tid) + 0, a0.x);
        atomicAdd(dst + 4 * (0 * 256 + tid) + 1, a0.y);
        atomicAdd(dst + 4 * (0 * 256 + tid) + 2, a0.z);
        atomicAdd(dst + 4 * (0 * 256 + tid) + 3, a0.w);
        atomicAdd(dst + 4 * (1 * 256 + tid) + 0, a1.x);
        atomicAdd(dst + 4 * (1 * 256 + tid) + 1, a1.y);
        atomicAdd(dst + 4 * (1 * 256 + tid) + 2, a1.z);
        atomicAdd(dst + 4 * (1 * 256 + tid) + 3, a1.w);
        atomicAdd(dst + 4 * (2 * 256 + tid) + 0, a2.x);
        atomicAdd(dst + 4 * (2 * 256 + tid) + 1, a2.y);
        atomicAdd(dst + 4 * (2 * 256 + tid) + 2, a2.z);
        atomicAdd(dst + 4 * (2 * 256 + tid) + 3, a2.w);
        atomicAdd(dst + 4 * (3 * 256 + tid) + 0, a3.x);
        atomicAdd(dst + 4 * (3 * 256 + tid) + 1, a3.y);
        atomicAdd(dst + 4 * (3 * 256 + tid) + 2, a3.z);
        atomicAdd(dst + 4 * (3 * 256 + tid) + 3, a3.w);
    } else {
        // ---------------- gate-contraction: one block per kb ----------------
        const int kb = blockIdx.x - NCOLSUM;  // [0, 1024)
        float acc[8][4];
#pragma unroll
        for (int b = 0; b < 8; ++b)
#pragma unroll
            for (int j = 0; j < 4; ++j) acc[b][j] = 0.f;

#pragma unroll
        for (int chunk = 0; chunk < CB / 256; ++chunk) {
            const int cb = chunk * 256 + tid;
            float w4[4];
#pragma unroll
            for (int j = 0; j < 4; ++j) {
                float4 w = Wv[(size_t)(4 * kb + j) * CB + cb];  // W[4kb+j, 4cb..4cb+3]
                w4[j] = (w.x + w.y) + (w.z + w.w);
            }
#pragma unroll
            for (int b = 0; b < 8; ++b) {
                float g = G[((size_t)b * KB + kb) * CB + cb];
#pragma unroll
                for (int j = 0; j < 4; ++j) acc[b][j] += g * w4[j];
            }
        }

        // reduce 32 accumulators (b,j) across 256 threads: wave butterfly + LDS
        __shared__ float lds[4][32];
        const int lane = tid & 63, wid = tid >> 6;
#pragma unroll
        for (int v = 0; v < 32; ++v) {
            float x = acc[v >> 2][v & 3];
#pragma unroll
            for (int o = 1; o < 64; o <<= 1) x += __shfl_xor(x, o, 64);
            if (lane == 0) lds[wid][v] = x;
        }
        __syncthreads();
        if (tid < 32) {
            float r = lds[0][tid] + lds[1][tid] + lds[2][tid] + lds[3][tid];
            const int b = tid >> 2, j = tid & 3;
            wg[(size_t)b * WIDTH + 4 * kb + j] = r;  // deterministic direct store
        }
    }
}

// ---------------------------------------------------------------------------
// Final: s = sum_{b,k} xs[b,k]*wg[b,k]; out = s*s. One 1024-thread block.
// ---------------------------------------------------------------------------
__global__ __launch_bounds__(1024) void final_kernel(const float4* __restrict__ xs4,
                                                     const float4* __restrict__ wg4,
                                                     float* __restrict__ out) {
    float acc = 0.f;
#pragma unroll
    for (int rep = 0; rep < BATCH * WIDTH / 4 / 1024; ++rep) {
        int i = rep * 1024 + threadIdx.x;
        float4 a = xs4[i], b = wg4[i];
        acc += a.x * b.x + a.y * b.y + a.z * b.z + a.w * b.w;
    }
    __shared__ float red[1024];
    red[threadIdx.x] = acc;
    __syncthreads();
    for (int o = 512; o > 0; o >>= 1) {
        if (threadIdx.x < o) red[threadIdx.x] += red[threadIdx.x + o];
        __syncthreads();
    }
    if (threadIdx.x == 0) {
        float s = red[0];
        out[0] = s * s;
    }
}

extern "C" void kernel_launch(void* const* d_in, const int* in_sizes, int n_in,
                              void* d_out, int out_size, void* d_ws, size_t ws_size,
                              hipStream_t stream) {
    const float* X = (const float*)d_in[0];  // (8, 2048, 4096)
    const float* W = (const float*)d_in[1];  // (4096, 4096)
    const float* G = (const float*)d_in[2];  // (8, 1024, 1024)
    float* out = (float*)d_out;              // scalar

    float* xs = (float*)d_ws;                // 8*4096 floats (atomic targets)
    float* wg = xs + BATCH * WIDTH;          // 8*4096 floats (direct stores)

    // zero only the atomic accumulator region — wg is fully overwritten
    hipMemsetAsync(xs, 0, (size_t)BATCH * WIDTH * sizeof(float), stream);

    fused_kernel<<<NCOLSUM + KB, 256, 0, stream>>>((const float4*)X, (const float4*)W, G, xs, wg);

    final_kernel<<<1, 1024, 0, stream>>>((const float4*)xs, (const float4*)wg, out);
}